// Round 13
// baseline (13755.296 us; speedup 1.0000x reference)
//
#include <hip/hip_runtime.h>
#include <hip/hip_bf16.h>

// LSTM: B=64, S=512, H=768, L=2. Persistent scan per layer, 16 waves/WG.
//   waves 0-11 (h):  K=64 slice each -> 12w loads + 4h loads + 18 MFMA per
//                    step = fits the 84-VGPR budget in ONE load volley
//                    (rounds 8-12: 6 waves x K=384 chains serialized).
//   waves 12-14 (x): K=256 slice each for all 3 tiles, one step ahead into a
//                    4-slot LDS ring; double as finalizers (tile = wave).
//   wave 15: flag poller.
// Weights pre-split (hi|lo bf16 uint4 pairs) into per-(wid,wave,slice)
// coalesced blocks; per-XCD working set 2.3MB -> L2-resident.
// h exchange: MALL-bypass relaxed-agent stores + vmcnt ack + flag; consumers
// plain cached loads on write-once streams (round-5-proven), or 2-slot
// bypass ring for L1 if ws is small (round-4-proven).

#define HID 768
#define FH  3072
#define SEQ 512
#define BAT 64
#define GB  16
#define WPG 64
#define NWG 256
#define TPB 1024         // 16 waves

typedef __attribute__((ext_vector_type(8))) __bf16 bf16x8;
typedef __attribute__((ext_vector_type(4))) float f32x4;
typedef unsigned int u32;
typedef unsigned long long u64;

__device__ __forceinline__ float sigm(float z) { return 1.f / (1.f + __expf(-z)); }
__device__ __forceinline__ float tanh_fast(float x) {
  float a = fabsf(x);
  float e = __expf(-2.f * a);
  float t = (1.f - e) / (1.f + e);
  return copysignf(t, x);
}
__device__ __forceinline__ unsigned short bfbits(__bf16 b) {
  union { __bf16 b; unsigned short s; } u; u.b = b; return u.s;
}
__device__ __forceinline__ __bf16 bits2bf(unsigned short s) {
  union { unsigned short s; __bf16 b; } u; u.s = s; return u.b;
}
__device__ __forceinline__ u32 packsplit(float v) {
  __bf16 h = (__bf16)v;
  __bf16 l = (__bf16)(v - (float)h);
  return ((u32)bfbits(h) << 16) | (u32)bfbits(l);
}
__device__ __forceinline__ void split8(const float* p, bf16x8& hi, bf16x8& lo) {
  const float4* q = (const float4*)p;
  float4 a = q[0], b = q[1];
  float v[8] = {a.x, a.y, a.z, a.w, b.x, b.y, b.z, b.w};
#pragma unroll
  for (int i = 0; i < 8; ++i) {
    __bf16 h = (__bf16)v[i];
    hi[i] = h;
    lo[i] = (__bf16)(v[i] - (float)h);
  }
}
__device__ __forceinline__ void unpack8(const u32 w[8], bf16x8& hi, bf16x8& lo) {
#pragma unroll
  for (int i = 0; i < 8; ++i) {
    hi[i] = bits2bf((unsigned short)(w[i] >> 16));
    lo[i] = bits2bf((unsigned short)(w[i] & 0xffffu));
  }
}
__device__ __forceinline__ bf16x8 q2b(uint4 q) {
  union { uint4 q; bf16x8 v; } u; u.q = q; return u.v;
}
__device__ __forceinline__ uint4 b2q(bf16x8 v) {
  union { bf16x8 v; uint4 q; } u; u.v = v; return u.q;
}

// ---- prep: split Wih+Whh (both layers) into per-wave slice layout ----
// wih slice = ((layer*64+wid)*3 + xw)*24 + t*8 + c   (k = xw*256 + c*32)
// whh slice = ((layer*64+wid)*12 + j)*6 + t*2 + c    (k = j*64  + c*32)
// slice data: 64 lanes x (hi uint4, lo uint4) = 512 u32, lane at lane*8.
__global__ void pack_w(const float* __restrict__ Wih,
                       const float* __restrict__ Whh,
                       u32* __restrict__ wpk) {
  int g = blockIdx.x * blockDim.x + threadIdx.x;
  const int NT = 2 * 9216 * 64;
  if (g >= NT) return;
  int lane = g & 63;
  int sl = g >> 6;                 // [0, 18432)
  int region = sl / 9216;          // 0 = wih, 1 = whh
  int sr = sl % 9216;
  int l15 = lane & 15, lhi = lane >> 4;
  int k, t, wid, layer;
  const float* W;
  if (region == 0) {
    int c  = sr % 8;
    t      = (sr / 8) % 3;
    int xw = (sr / 24) % 3;
    wid    = (sr / 72) % 64;
    layer  = sr / 4608;
    k = xw*256 + c*32 + lhi*8;
    W = Wih + (size_t)layer*FH*HID;
  } else {
    int c  = sr % 2;
    t      = (sr / 2) % 3;
    int j  = (sr / 6) % 12;
    wid    = (sr / 72) % 64;
    layer  = sr / 4608;
    k = j*64 + c*32 + lhi*8;
    W = Whh + (size_t)layer*FH*HID;
  }
  int row = (l15 & 3)*HID + wid*12 + t*4 + (l15 >> 2);
  bf16x8 hi, lo;
  split8(W + (size_t)row*HID + k, hi, lo);
  u32* dst = wpk + ((size_t)region*9216 + sr)*512 + lane*8;
  *(uint4*)dst       = b2q(hi);
  *(uint4*)(dst + 4) = b2q(lo);
}

#define MFMA16 __builtin_amdgcn_mfma_f32_16x16x32_bf16

template<int XFMT, int WRITE_OUT, int RING>
__attribute__((amdgpu_waves_per_eu(4, 4)))
__global__ void __launch_bounds__(TPB)
lstm_scan(const float* __restrict__ xf,   // XFMT==0: raw x [64][512][768] fp32
          const u32* __restrict__ xp,     // XFMT==1: packed pairs [512][64][768]
          const float* __restrict__ mask, // [64][512]
          const u32* __restrict__ wipk,   // pre-split Wih, this layer
          const u32* __restrict__ whpk,   // pre-split Whh, this layer
          const float* __restrict__ bih,
          const float* __restrict__ bhh,
          u32* __restrict__ hdst,         // RING? [2][64][768] : [512][64][768]
          const u32* __restrict__ hsrc,   // same buffer
          float* __restrict__ out_f,      // WRITE_OUT: [64][512][768]
          float* __restrict__ hn, float* __restrict__ cn,
          int* __restrict__ flags)        // [NWG] this layer, zeroed
{
  __shared__ f32x4 xring[4][3][3][64];    // [slot][xw][tile][lane] 36864 B
  __shared__ f32x4 hpart[12][3][64];      // [j][tile][lane]        36864 B
  __shared__ f32x4 padlds[512];           // 8192 B -> 81920 B total (1 blk/CU)

  const int wg  = blockIdx.x;
  const int grp = wg >> 6;
  const int wid = wg & 63;
  const int tid = threadIdx.x;
  const int wv  = tid >> 6;        // 0..15
  const int l   = tid & 63;
  const int l15 = l & 15;
  const int lhi = l >> 4;

  if ((int)blockIdx.x == -1) padlds[tid & 511] = hpart[0][0][0];  // keep pad

  const bool ish  = (wv < 12);
  const bool isxw = (wv >= 12 && wv < 15);
  const int j  = wv;               // h K-slice (valid when ish)
  const int xw = wv - 12;          // x K-slice / finalize tile (valid when isxw)

  const int batch = grp*GB + l15;
  const u32* wbj = whpk + (size_t)(wid*12 + (ish  ? j  : 0))*6*512;
  const u32* wbx = wipk + (size_t)(wid*3  + (isxw ? xw : 0))*24*512;

  // finalizer (x-wave) output ownership
  const int colO = wid*12 + (isxw ? xw : 0)*4 + lhi;
  float bias4[4] = {0.f, 0.f, 0.f, 0.f};
  if (isxw) {
#pragma unroll
    for (int r = 0; r < 4; ++r) bias4[r] = bih[r*HID + colO] + bhh[r*HID + colO];
  }
  const float* mrow = mask + batch*SEQ;
  int* gflags = flags + grp*WPG;
  float cstate = 0.f;

  // x-projection for step sstep into ring slot (x-waves only)
  auto xproj = [&](int sstep, int slot) {
    f32x4 a0{0.f,0.f,0.f,0.f}, a1{0.f,0.f,0.f,0.f}, a2{0.f,0.f,0.f,0.f};
#pragma unroll
    for (int c = 0; c < 8; ++c) {
      bf16x8 bhi, blo;
      if constexpr (XFMT == 0) {
        const float* src = xf + ((size_t)batch*SEQ + sstep)*HID + xw*256 + c*32 + lhi*8;
        split8(src, bhi, blo);
      } else {
        const u32* src = xp + ((size_t)sstep*BAT + batch)*HID + xw*256 + c*32 + lhi*8;
        uint4 A = *(const uint4*)src, B = *(const uint4*)(src + 4);
        u32 w[8] = {A.x,A.y,A.z,A.w,B.x,B.y,B.z,B.w};
        unpack8(w, bhi, blo);
      }
      {
        const uint4* wp = (const uint4*)(wbx + (size_t)(0*8 + c)*512 + l*8);
        bf16x8 Ah = q2b(wp[0]), Al = q2b(wp[1]);
        a0 = MFMA16(Ah, bhi, a0, 0,0,0); a0 = MFMA16(Al, bhi, a0, 0,0,0); a0 = MFMA16(Ah, blo, a0, 0,0,0);
      }
      {
        const uint4* wp = (const uint4*)(wbx + (size_t)(1*8 + c)*512 + l*8);
        bf16x8 Ah = q2b(wp[0]), Al = q2b(wp[1]);
        a1 = MFMA16(Ah, bhi, a1, 0,0,0); a1 = MFMA16(Al, bhi, a1, 0,0,0); a1 = MFMA16(Ah, blo, a1, 0,0,0);
      }
      {
        const uint4* wp = (const uint4*)(wbx + (size_t)(2*8 + c)*512 + l*8);
        bf16x8 Ah = q2b(wp[0]), Al = q2b(wp[1]);
        a2 = MFMA16(Ah, bhi, a2, 0,0,0); a2 = MFMA16(Al, bhi, a2, 0,0,0); a2 = MFMA16(Ah, blo, a2, 0,0,0);
      }
    }
    xring[slot][xw][0][l] = a0;
    xring[slot][xw][1][l] = a1;
    xring[slot][xw][2][l] = a2;
  };

  // ---- prologue: ring slot 0 ----
  if (isxw) xproj(0, 0);
  __syncthreads();

#pragma unroll 1
  for (int s = 0; s < SEQ; ++s) {
    // ---- P: wave 15 polls for h(s-1) ----
    if (wv == 15 && s > 0) {
      while (true) {
        int v = __hip_atomic_load(gflags + l, __ATOMIC_RELAXED, __HIP_MEMORY_SCOPE_AGENT);
        if (__all(v >= s)) break;
        __builtin_amdgcn_s_sleep(1);
      }
    }
    __syncthreads();   // b1: h(s-1) globally readable

    // ---- C: h-waves K=64 GEMM; x-waves compute x(s+1) ----
    if (ish && s > 0) {
      f32x4 a0{0.f,0.f,0.f,0.f}, a1{0.f,0.f,0.f,0.f}, a2{0.f,0.f,0.f,0.f};
#pragma unroll
      for (int c = 0; c < 2; ++c) {
        u32 w[8];
        if constexpr (RING) {
          const u64* sp = (const u64*)(hsrc + ((size_t)((s-1)&1)*BAT + batch)*HID + j*64 + c*32 + lhi*8);
          u64 qa = __hip_atomic_load(sp,   __ATOMIC_RELAXED, __HIP_MEMORY_SCOPE_AGENT);
          u64 qb = __hip_atomic_load(sp+1, __ATOMIC_RELAXED, __HIP_MEMORY_SCOPE_AGENT);
          u64 qc = __hip_atomic_load(sp+2, __ATOMIC_RELAXED, __HIP_MEMORY_SCOPE_AGENT);
          u64 qd = __hip_atomic_load(sp+3, __ATOMIC_RELAXED, __HIP_MEMORY_SCOPE_AGENT);
          w[0]=(u32)qa; w[1]=(u32)(qa>>32); w[2]=(u32)qb; w[3]=(u32)(qb>>32);
          w[4]=(u32)qc; w[5]=(u32)(qc>>32); w[6]=(u32)qd; w[7]=(u32)(qd>>32);
        } else {
          const u32* sp = hsrc + ((size_t)(s-1)*BAT + batch)*HID + j*64 + c*32 + lhi*8;
          uint4 A = *(const uint4*)sp, B = *(const uint4*)(sp + 4);
          w[0]=A.x; w[1]=A.y; w[2]=A.z; w[3]=A.w;
          w[4]=B.x; w[5]=B.y; w[6]=B.z; w[7]=B.w;
        }
        bf16x8 bhi, blo;
        unpack8(w, bhi, blo);
        {
          const uint4* wp = (const uint4*)(wbj + (size_t)(0*2 + c)*512 + l*8);
          bf16x8 Ah = q2b(wp[0]), Al = q2b(wp[1]);
          a0 = MFMA16(Ah, bhi, a0, 0,0,0); a0 = MFMA16(Al, bhi, a0, 0,0,0); a0 = MFMA16(Ah, blo, a0, 0,0,0);
        }
        {
          const uint4* wp = (const uint4*)(wbj + (size_t)(1*2 + c)*512 + l*8);
          bf16x8 Ah = q2b(wp[0]), Al = q2b(wp[1]);
          a1 = MFMA16(Ah, bhi, a1, 0,0,0); a1 = MFMA16(Al, bhi, a1, 0,0,0); a1 = MFMA16(Ah, blo, a1, 0,0,0);
        }
        {
          const uint4* wp = (const uint4*)(wbj + (size_t)(2*2 + c)*512 + l*8);
          bf16x8 Ah = q2b(wp[0]), Al = q2b(wp[1]);
          a2 = MFMA16(Ah, bhi, a2, 0,0,0); a2 = MFMA16(Al, bhi, a2, 0,0,0); a2 = MFMA16(Ah, blo, a2, 0,0,0);
        }
      }
      hpart[j][0][l] = a0;
      hpart[j][1][l] = a1;
      hpart[j][2][l] = a2;
    }
    if (isxw && s + 1 < SEQ) xproj(s + 1, (s + 1) & 3);
    __syncthreads();   // b2: hpart + xring(s) ready

    // ---- F: x-waves finalize tile xw ----
    if (isxw) {
      f32x4 z = xring[s & 3][0][xw][l] + xring[s & 3][1][xw][l] + xring[s & 3][2][xw][l];
      if (s > 0) {
#pragma unroll
        for (int jj = 0; jj < 12; ++jj) z = z + hpart[jj][xw][l];
      }
      float zi = z[0] + bias4[0], zf = z[1] + bias4[1];
      float zg = z[2] + bias4[2], zo = z[3] + bias4[3];
      float iv = sigm(zi), fv = sigm(zf), gv = tanh_fast(zg), ov = sigm(zo);
      float c  = fv*cstate + iv*gv;
      float hv = ov * tanh_fast(c);
      float m  = mrow[s];
      hv *= m; c *= m; cstate = c;

      u32 hw = packsplit(hv);
      size_t wrow = RING ? ((size_t)(s & 1)*BAT + batch)*HID + colO
                         : ((size_t)s*BAT + batch)*HID + colO;
      __hip_atomic_store(hdst + wrow, hw,
                         __ATOMIC_RELAXED, __HIP_MEMORY_SCOPE_AGENT);
      if constexpr (WRITE_OUT) {
        __builtin_nontemporal_store(hv, out_f + ((size_t)batch*SEQ + s)*HID + colO);
      }
      if (s == SEQ - 1) {
        hn[batch*HID + colO] = hv;
        cn[batch*HID + colO] = c;
      }
      asm volatile("s_waitcnt vmcnt(0)" ::: "memory");  // h at MALL before flag
    }
    __syncthreads();   // b3
    if (tid == 0)
      __hip_atomic_store(gflags + wid, s + 1,
                         __ATOMIC_RELAXED, __HIP_MEMORY_SCOPE_AGENT);
  }
}

extern "C" void kernel_launch(void* const* d_in, const int* in_sizes, int n_in,
                              void* d_out, int out_size, void* d_ws, size_t ws_size,
                              hipStream_t stream) {
  const float* x    = (const float*)d_in[0];
  const float* mask = (const float*)d_in[1];
  const float* Wih  = (const float*)d_in[2];
  const float* Whh  = (const float*)d_in[3];
  const float* bih  = (const float*)d_in[4];
  const float* bhh  = (const float*)d_in[5];
  float* out = (float*)d_out;

  char* ws = (char*)d_ws;
  const size_t WPK_B   = (size_t)2*9216*512*4;       // 37,748,736
  const size_t STREAM_B = (size_t)SEQ*BAT*HID*4;     // 100,663,296
  const size_t RING_B  = (size_t)2*BAT*HID*4;        // 393,216

  u32* wpk = (u32*)ws;
  u32* opk = (u32*)(ws + WPK_B);                     // L0 h-stream = L1 input
  const bool big = ws_size >= WPK_B + 2*STREAM_B + 4096;
  u32* h1  = (u32*)(ws + WPK_B + STREAM_B);          // L1 h store
  int* flags = big ? (int*)(ws + WPK_B + 2*STREAM_B)
                   : (int*)(ws + WPK_B + STREAM_B + RING_B);

  (void)hipMemsetAsync(flags, 0, 2*NWG*sizeof(int), stream);
  pack_w<<<4608, 256, 0, stream>>>(Wih, Whh, wpk);

  float* hn = out + 25165824;                        // [2][64][768]
  float* cn = out + 25165824 + 98304;

  const u32* wipk0 = wpk;
  const u32* wipk1 = wpk + (size_t)4608*512;
  const u32* whpk0 = wpk + (size_t)9216*512;
  const u32* whpk1 = wpk + (size_t)13824*512;

  // ---- layer 0: raw fp32 x, h-stream -> opk (plain-cached reads) ----
  lstm_scan<0, 0, 0><<<dim3(NWG), dim3(TPB), 0, stream>>>(
      x, nullptr, mask, wipk0, whpk0, bih, bhh,
      opk, opk, nullptr, hn, cn, flags);

  // ---- layer 1: opk input ----
  if (big) {
    lstm_scan<1, 1, 0><<<dim3(NWG), dim3(TPB), 0, stream>>>(
        nullptr, opk, mask, wipk1, whpk1, bih + FH, bhh + FH,
        h1, h1, out, hn + 49152, cn + 49152, flags + NWG);
  } else {
    lstm_scan<1, 1, 1><<<dim3(NWG), dim3(TPB), 0, stream>>>(
        nullptr, opk, mask, wipk1, whpk1, bih + FH, bhh + FH,
        h1, h1, out, hn + 49152, cn + 49152, flags + NWG);
  }
}